// Round 13
// baseline (98.342 us; speedup 1.0000x reference)
//
#include <hip/hip_runtime.h>
#include <stdint.h>
#include <math.h>

// Soft-DTW forward, B=64, N=M=512, gamma=1 — probability-domain wavefront DP.
// P = exp(-R): P_new = exp(-d)*(Pa+Pb+Pc); chain dpp->mul->cndmask->fma->fma.
// Per-lane scale E + per-chunk renorm + exact ldexp inter-wave reconcile.
// Coalesced bf16 LDS ring for D. EXACT round-10 structure (CHUNK=16, DELTA=96,
// tied-vmcnt staging, raw lgkmcnt(0)+s_barrier) — rounds 11/12's CHUNK=32
// rewrite failed correctness twice; reverted.
//
// ROUND 13 DELTA (wave-private, order-safe only):
//  1. Software-pipelined LDS reads: the ring words (own wave's PRIVATE ring —
//     zero cross-wave hazard) and the bnd/bndE boundary reads (verified >=1
//     barrier after writer's store) for chunk g+1 are issued at the END of
//     chunk g, after STAGE_WRITE. Their ~120-300cy latency lands under the
//     barrier-wait + next chunk's E-block instead of stalling the chunk top.
//  2. Shift-based bf16 extraction: d = (wd << sh) & 0xffff0000 with per-lane
//     precomputed sh (2 VALU) replaces shift+and+cndmask (3 VALU) per value.
//  3. Prefetch state in structs with literal-only indexing (register-safe).
//
// 64 blocks (1/batch) x 4 waves. Lane l of wave w owns DP rows 128w+2l+1/+2.

namespace {
constexpr int NWAVE = 4;
constexpr int DELTA = 96;                     // wave-to-wave step offset
constexpr int MCOLS = 512;
constexpr int LOCAL = MCOLS + 63;             // 575 steps per wave
constexpr int NCHUNK = 54;                    // 54*16=864 >= 3*96+575=863, even
constexpr int BROW = 608;                     // bnd: live 0..511, trash 544..607
constexpr int RW = 65;                        // ring words/row: 64 data + 1 pad
constexpr float LN2 = 0.69314718055994530942f;
constexpr float L2E = 1.44269504088896340736f;
}

using f4 = __attribute__((ext_vector_type(4))) float;
using u32x4 = __attribute__((ext_vector_type(4))) unsigned int;

__device__ __forceinline__ float dpp_shr1(float v) {
  // lane n <- lane n-1 (wave_shr:1); lane 0 reads 0 (bound_ctrl) = P(INF)
  return __int_as_float(__builtin_amdgcn_update_dpp(0, __float_as_int(v), 0x138, 0xf, 0xf, true));
}
__device__ __forceinline__ int dpp_shr1_i(int v) {
  return __builtin_amdgcn_update_dpp(0, v, 0x138, 0xf, 0xf, true);
}
__device__ __forceinline__ float rdlane(float v, int lane) {
  return __int_as_float(__builtin_amdgcn_readlane(__float_as_int(v), lane));
}
// pack 2 f32 -> 1 u32 of 2 bf16 (RNE); low half = first operand (even col)
__device__ __forceinline__ void packw(const f4& g, uint32_t* p) {
  uint32_t w0, w1;
  asm("v_cvt_pk_bf16_f32 %0, %1, %2" : "=v"(w0) : "v"(g[0]), "v"(g[1]));
  asm("v_cvt_pk_bf16_f32 %0, %1, %2" : "=v"(w1) : "v"(g[2]), "v"(g[3]));
  p[0] = w0;
  p[1] = w1;
}

// Double-buffered per-chunk prefetch state. All indices are LITERAL after
// unroll -> SROA keeps this in registers (rule #20 safe).
struct Pref {
  uint32_t W[9];  // ring words, row 2l
  uint32_t V[9];  // ring words, row 2l+1
  float bv;       // boundary value brd[tn + (l&15)]
  int Eb;         // its writer-chunk scale
  int Ead;        // brdE[3] for whole-wave adoption at tn==0
};

__device__ __forceinline__ void prefetch(Pref& P, int tn, int w, int l,
                                         const uint32_t* __restrict__ q1,
                                         const uint32_t* __restrict__ q2,
                                         const float* __restrict__ brd,
                                         const int* __restrict__ brdE) {
  if (tn < 0 || tn >= LOCAL) return;
  const int e0 = ((tn - l) & 127) >> 1;
#pragma unroll
  for (int k = 0; k < 9; ++k) {
    P.W[k] = q1[(e0 + k) & 63];
    P.V[k] = q2[(e0 + k) & 63];
  }
  if (w > 0 && tn < 512) {
    const int j = l & 15;
    P.bv = brd[tn + j];
    // col tn+j finalized during writer-local chunk (tn>>4)+(j?4:3)
    P.Eb = brdE[(tn >> 4) + (j ? 4 : 3)];
    P.Ead = brdE[3];
  }
}

// 16 DP steps over the current chunk. G = guarded (fill/drain) variant.
// d-values from prefetched bf16 ring words: even step s: word s>>1, half par;
// odd step: word (s+par)>>1, half !par. Extraction via per-lane shift.
template <bool G>
__device__ __forceinline__ void steps16(const Pref& P, int t0, int l, int tid,
                                        bool isL0, bool par, uint32_t shE,
                                        uint32_t shO, float rsc, float curv,
                                        float* __restrict__ bwr,
                                        float& x1, float& x2, float& areg) {
#pragma unroll
  for (int s = 0; s < 16; ++s) {
    const int c = t0 + s - l;
    uint32_t wd, vd;
    if ((s & 1) == 0) {
      wd = P.W[s >> 1];
      vd = P.V[s >> 1];
    } else {
      wd = par ? P.W[(s + 1) >> 1] : P.W[s >> 1];
      vd = par ? P.V[(s + 1) >> 1] : P.V[s >> 1];
    }
    const uint32_t sh = (s & 1) ? shO : shE;
    const float d1 = __uint_as_float((wd << sh) & 0xffff0000u);
    const float d2 = __uint_as_float((vd << sh) & 0xffff0000u);
    // off-chain: exp(-d) = exp2(-d*log2e)
    const float k1 = __builtin_amdgcn_exp2f(d1 * -L2E);
    const float k2 = __builtin_amdgcn_exp2f(d2 * -L2E);
    float aa = areg;
    if (G) aa = (tid == 0 && c == 0) ? 1.0f : aa;  // P(R[0][0]=0)=1 seed
    const float k1s1 = k1 * (aa + x1);  // off-chain
    const float k2s2 = k2 * (x1 + x2);  // off-chain
    // chain: dpp -> mul -> cndmask -> fma -> fma
    const float bsh = dpp_shr1(x2) * rsc;           // lane l-1's x2, rescaled
    const float bb = isL0 ? rdlane(curv, s) : bsh;  // lane0: wave-boundary
    const float x1n = fmaf(k1, bb, k1s1);   // row i1: k1*(aa+x1+bb)
    const float x2n = fmaf(k2, x1n, k2s2);  // row i2: k2*(x1+x2+x1n)
    if (G) {
      const bool act = (unsigned)c < 512u;
      const int idx = act ? c : (int)(544u + ((unsigned)c & 63u));  // OOB->trash
      bwr[idx] = x2n;
      x1 = act ? x1n : x1;   // garbage ring data for inactive c discarded here
      x2 = act ? x2n : x2;
    } else {
      bwr[c] = x2n;  // all lanes store; lane 63 (step c+63) writes last
      x1 = x1n;
      x2 = x2n;
    }
    areg = bb;  // next step's diagonal (incl. lane-0 boundary value)
  }
}

// Coalesced stage of col-block [CS, CS+16) for this wave's 128 rows:
// instr i, lane j: row 16i+(j>>2), 16B at col CS+(j&3)*4 -> 16 lines/instr.
#define STAGE_ISSUE(CS) do {                                                        \
    const int v0_ = voBase + ((CS) << 2);                                           \
    asm volatile("buffer_load_dwordx4 %0, %1, %2, 0 offen" : "=v"(g0) : "v"(v0_), "s"(srd));             \
    asm volatile("buffer_load_dwordx4 %0, %1, %2, 0 offen" : "=v"(g1) : "v"(v0_ + 1*32768), "s"(srd));   \
    asm volatile("buffer_load_dwordx4 %0, %1, %2, 0 offen" : "=v"(g2) : "v"(v0_ + 2*32768), "s"(srd));   \
    asm volatile("buffer_load_dwordx4 %0, %1, %2, 0 offen" : "=v"(g3) : "v"(v0_ + 3*32768), "s"(srd));   \
    asm volatile("buffer_load_dwordx4 %0, %1, %2, 0 offen" : "=v"(g4) : "v"(v0_ + 4*32768), "s"(srd));   \
    asm volatile("buffer_load_dwordx4 %0, %1, %2, 0 offen" : "=v"(g5) : "v"(v0_ + 5*32768), "s"(srd));   \
    asm volatile("buffer_load_dwordx4 %0, %1, %2, 0 offen" : "=v"(g6) : "v"(v0_ + 6*32768), "s"(srd));   \
    asm volatile("buffer_load_dwordx4 %0, %1, %2, 0 offen" : "=v"(g7) : "v"(v0_ + 7*32768), "s"(srd));   \
} while (0)

// vmcnt(0) is safe here: the 8 stage loads are the only in-flight VMEM.
#define STAGE_WRITE(CS) do {                                                        \
    asm volatile("s_waitcnt vmcnt(0)"                                               \
        : "+v"(g0), "+v"(g1), "+v"(g2), "+v"(g3),                                   \
          "+v"(g4), "+v"(g5), "+v"(g6), "+v"(g7)::);                                \
    const int ew_ = ((((CS) & 127) >> 1) + ((l & 3) << 1));                         \
    uint32_t* rp_ = &dring[w][l >> 2][ew_];                                         \
    packw(g0, rp_);            packw(g1, rp_ + 16 * RW);                            \
    packw(g2, rp_ + 32 * RW);  packw(g3, rp_ + 48 * RW);                            \
    packw(g4, rp_ + 64 * RW);  packw(g5, rp_ + 80 * RW);                            \
    packw(g6, rp_ + 96 * RW);  packw(g7, rp_ + 112 * RW);                           \
} while (0)

// One chunk: stage-issue -> compute (with prefetched PC) -> stage-write ->
// prefetch PN for the NEXT chunk -> barrier.
#define BODY(PC, PN, MC) do {                                                       \
    const int t0_ = 16 * (MC) - ow;                                                 \
    const bool doStage_ = (t0_ >= 0) && (t0_ <= 480);  /* stages [t0+16,t0+32) */   \
    if (doStage_) STAGE_ISSUE(t0_ + 16);                                            \
    if (t0_ >= 0 && t0_ < LOCAL) {                                                  \
      const int ENpre_ = dpp_shr1_i(E);                                             \
      const bool inact_ = (x1 == 0.0f) && (x2 == 0.0f);                             \
      if (w > 0 && t0_ == 0) E = PC.Ead;         /* whole-wave scale adoption */    \
      else if (inact_ && !isL0) E = ENpre_;      /* track left neighbor */          \
      float curv_ = 0.0f;                                                           \
      if (w > 0 && t0_ < 512) {                                                     \
        const int E0_ = __builtin_amdgcn_readfirstlane(E);                          \
        curv_ = ldexpf(PC.bv, PC.Eb - E0_);      /* exact scale reconcile */        \
      }                                                                             \
      if (l == 63) bwrE[t0_ >> 4] = E;           /* lane 63 makes final writes */   \
      const int EN2_ = dpp_shr1_i(E);                                               \
      int dE_ = EN2_ - E;                                                           \
      dE_ = dE_ < -126 ? -126 : (dE_ > 126 ? 126 : dE_);                            \
      const float rsc_ = __int_as_float((127 + dE_) << 23);                         \
      if (t0_ >= 64 && t0_ <= 496)                                                  \
        steps16<false>(PC, t0_, l, tid, isL0, par, shE, shO, rsc_, curv_, bwr,      \
                       x1, x2, areg);                                               \
      else                                                                          \
        steps16<true>(PC, t0_, l, tid, isL0, par, shE, shO, rsc_, curv_, bwr,       \
                      x1, x2, areg);                                                \
      /* per-lane renorm: recenter max(x1,x2) exponent to 2^-10 */                  \
      const int bx_ = (__float_as_int(x1) >> 23) & 255;                             \
      const int by_ = (__float_as_int(x2) >> 23) & 255;                             \
      int exm_ = bx_ > by_ ? bx_ : by_;                                             \
      int sh_ = (exm_ > 0) ? (117 - exm_) : 0;                                      \
      sh_ = sh_ < -110 ? -110 : sh_;                                                \
      const float sc_ = __int_as_float((127 + sh_) << 23);                          \
      x1 *= sc_; x2 *= sc_; areg *= sc_; E -= sh_;                                  \
    }                                                                               \
    if (doStage_) STAGE_WRITE(t0_ + 16);  /* vmcnt tie + cvt + ds_write */          \
    /* prefetch next chunk's LDS reads: ring is wave-private (in-order DS);  */     \
    /* bnd/bndE writer stores are >=1 barrier before this point (verified).  */     \
    prefetch(PN, t0_ + 16, w, l, q1p, q2p, brd, brdE);                              \
    /* barrier for bnd only; prefetch reads complete ~pipe-depth after the   */     \
    /* stage writes they follow — negligible added arrival delay.            */     \
    asm volatile("s_waitcnt lgkmcnt(0)\n\ts_barrier" ::: "memory");                 \
} while (0)

__global__ __launch_bounds__(256, 1) void sdtw_kernel(const float* __restrict__ D,
                                                      float* __restrict__ out) {
  static_assert(NCHUNK % 2 == 0, "loop is 2x unrolled");
  __shared__ uint32_t dring[NWAVE][128][RW];  // per-wave PRIVATE bf16 col ring
  __shared__ float bnd[NWAVE + 1][BROW];      // [4] = dump row for wave 3
  __shared__ int bndE[NWAVE][36];             // per-wave per-chunk lane-63 E
  const int tid = threadIdx.x;
  const int w = tid >> 6, l = tid & 63, b = blockIdx.x;

  u32x4 srd;  // raw buffer descriptor over D
  const uint64_t base = (uint64_t)(const void*)D;
  srd[0] = (unsigned)base;
  srd[1] = (unsigned)(base >> 32) & 0xffffu;  // stride=0
  srd[2] = 64u * 512u * 512u * 4u;            // num_records (bytes)
  srd[3] = 0x00020000u;

  const int ow = w * DELTA;
  const bool isL0 = (l == 0);
  const bool par = (l & 1) != 0;
  const uint32_t shE = par ? 0u : 16u;   // even-step extraction shift
  const uint32_t shO = par ? 16u : 0u;   // odd-step extraction shift
  // stage voffset base: row (128w + (l>>2)) of batch b, col-sub (l&3)*4
  const int voBase = (((b << 9) + (w << 7) + (l >> 2)) << 11) + ((l & 3) << 4);

  float* __restrict__ bwr = &bnd[(w == NWAVE - 1) ? NWAVE : w][0];
  float* __restrict__ brd = &bnd[(w == 0) ? 0 : (w - 1)][0];
  int* __restrict__ bwrE = &bndE[w][0];
  int* __restrict__ brdE = &bndE[(w == 0) ? 0 : (w - 1)][0];
  const uint32_t* __restrict__ q1p = &dring[w][2 * l][0];
  const uint32_t* __restrict__ q2p = &dring[w][2 * l + 1][0];

  float x1 = 0.0f, x2 = 0.0f, areg = 0.0f;  // P(INF) = 0
  int E = 0;                                // per-lane scale exponent

  f4 g0, g1, g2, g3, g4, g5, g6, g7;  // staged f32 col-block
  Pref PA{}, PB{};                    // double-buffered prefetch state

  // prologue: stage cols [0,16) (wave-private), then prefetch for chunk 0
  STAGE_ISSUE(0);
  STAGE_WRITE(0);
  prefetch(PA, -ow, w, l, q1p, q2p, brd, brdE);

  for (int mc = 0; mc < NCHUNK; mc += 2) {
    BODY(PA, PB, mc);
    BODY(PB, PA, mc + 1);
  }

  if (tid == NWAVE * 64 - 1) {
    // x2 * 2^E = exp(-R[512][512]);  v_log_f32 is log2
    const float Rv = -(__builtin_amdgcn_logf(x2) + (float)E);
    out[b] = Rv * LN2;
  }
}

extern "C" void kernel_launch(void* const* d_in, const int* in_sizes, int n_in,
                              void* d_out, int out_size, void* d_ws, size_t ws_size,
                              hipStream_t stream) {
  const float* D = (const float*)d_in[0];
  float* out = (float*)d_out;
  hipLaunchKernelGGL(sdtw_kernel, dim3(64), dim3(NWAVE * 64), 0, stream, D, out);
}

// Round 14
// 91.767 us; speedup vs baseline: 1.0716x; 1.0716x over previous
//
#include <hip/hip_runtime.h>
#include <stdint.h>
#include <math.h>

// Soft-DTW forward, B=64, N=M=512, gamma=1 — probability-domain wavefront DP.
// P = exp(-R): P_new = exp(-d)*(Pa+Pb+Pc); chain dpp->mul->cndmask->fma->fma.
// Per-lane scale E + per-chunk renorm + exact ldexp inter-wave reconcile.
// Coalesced bf16 LDS ring for D. R10/R13 skeleton (CHUNK=16, DELTA=96).
//
// ROUND 14 DELTA — halve LDS traffic, zero conflicts, count the lgkm wait:
//  1. bnd writes 16->4/chunk: lane 63 batches its 16 col values (vb regs +
//     carry cF) into 4x ds_write_b128; slack re-derived: publish at G-2 vs
//     read at end of G-1 (>=1 barrier). All-lane per-step stores removed.
//  2. stage writes 16->8 ds_write_b64 (RW 65->66: 8B-aligned, and the new
//     bank map is uniform 4 dwords/bank — fixes the measured 4-way conflict
//     (1.12M cy/dispatch, bank=(l>>2+2(l&3))%32 under RW=65)).
//  3. ring reads 18->9 ds_read2_b32 offset1:66 (W[k],V[k] same idx, adjacent
//     rows).
//  4. counted barrier wait: 12 asm prefetch reads (uniform, clamped idx),
//     `lgkmcnt(12); s_barrier` (DS FIFO: writes issued earlier are covered),
//     consume fence lgkmcnt(0)+sched_barrier at chunk top (rule #18).
//
// 64 blocks (1/batch) x 4 waves. Lane l of wave w owns DP rows 128w+2l+1/+2.

namespace {
constexpr int NWAVE = 4;
constexpr int DELTA = 96;                     // wave-to-wave step offset
constexpr int MCOLS = 512;
constexpr int LOCAL = MCOLS + 63;             // 575 steps per wave
constexpr int NCHUNK = 54;                    // 54*16=864 >= 3*96+575=863, even
constexpr int BROW = 528;                     // live 0..511 (+pad, 16-aligned)
constexpr int RW = 66;                        // ring words/row: 64 data + 2 pad
constexpr float LN2 = 0.69314718055994530942f;
constexpr float L2E = 1.44269504088896340736f;
}

using f4 = __attribute__((ext_vector_type(4))) float;
using u32x4 = __attribute__((ext_vector_type(4))) unsigned int;
using u2v = __attribute__((ext_vector_type(2))) unsigned int;

__device__ __forceinline__ float dpp_shr1(float v) {
  // lane n <- lane n-1 (wave_shr:1); lane 0 reads 0 (bound_ctrl) = P(INF)
  return __int_as_float(__builtin_amdgcn_update_dpp(0, __float_as_int(v), 0x138, 0xf, 0xf, true));
}
__device__ __forceinline__ int dpp_shr1_i(int v) {
  return __builtin_amdgcn_update_dpp(0, v, 0x138, 0xf, 0xf, true);
}
__device__ __forceinline__ float rdlane(float v, int lane) {
  return __int_as_float(__builtin_amdgcn_readlane(__float_as_int(v), lane));
}
// pack 4 f32 -> uint2 of 4 bf16 (RNE); low half of each word = even col
__device__ __forceinline__ uint2 packw2(const f4& g) {
  uint32_t a, b;
  asm("v_cvt_pk_bf16_f32 %0, %1, %2" : "=v"(a) : "v"(g[0]), "v"(g[1]));
  asm("v_cvt_pk_bf16_f32 %0, %1, %2" : "=v"(b) : "v"(g[2]), "v"(g[3]));
  return make_uint2(a, b);
}

// Double-buffered per-chunk prefetch state (literal-indexed -> registers).
struct Pref {
  uint32_t W[9];  // ring words, row 2l
  uint32_t V[9];  // ring words, row 2l+1
  float bv;       // boundary value brd[tn + (l&15)]
  int Eb;         // its writer-chunk scale
  int Ead;        // brdE[3] for whole-wave adoption at tn==0
};

// EXACTLY 12 asm DS reads (uniform count; clamped indices when tn invalid —
// values consumed only when valid). First read carries "memory" so compiler
// stores cannot sink below; reads are ordered before the lgkmcnt(12).
__device__ __forceinline__ void prefetch_asm(Pref& P, int tn, int w, int l,
                                             uint32_t ringB, uint32_t brdB,
                                             uint32_t brdEB) {
  int tnc = tn < 0 ? 0 : (tn > LOCAL - 1 ? LOCAL - 1 : tn);
  const int e0 = ((tnc - l) & 127) >> 1;
  u2v p0, p1, p2, p3, p4, p5, p6, p7, p8;
  uint32_t a0 = ringB + (((e0 + 0) & 63) << 2);
  asm volatile("ds_read2_b32 %0, %1 offset0:0 offset1:66" : "=v"(p0) : "v"(a0) : "memory");
#define RD2(P_, K_) { uint32_t a_ = ringB + (((e0 + (K_)) & 63) << 2);              \
    asm volatile("ds_read2_b32 %0, %1 offset0:0 offset1:66" : "=v"(P_) : "v"(a_)); }
  RD2(p1, 1) RD2(p2, 2) RD2(p3, 3) RD2(p4, 4) RD2(p5, 5) RD2(p6, 6) RD2(p7, 7) RD2(p8, 8)
#undef RD2
  const int j = l & 15;
  int bi = tnc + j; bi = bi > 511 ? 511 : bi;
  uint32_t bvu, ebu, eau;
  { uint32_t a_ = brdB + (bi << 2);
    asm volatile("ds_read_b32 %0, %1" : "=v"(bvu) : "v"(a_)); }
  int ei = (tnc >> 4) + (j ? 4 : 3); ei = ei > 35 ? 35 : ei;
  { uint32_t a_ = brdEB + (ei << 2);
    asm volatile("ds_read_b32 %0, %1" : "=v"(ebu) : "v"(a_)); }
  asm volatile("ds_read_b32 %0, %1" : "=v"(eau) : "v"(brdEB + 12));
  P.W[0] = p0[0]; P.V[0] = p0[1]; P.W[1] = p1[0]; P.V[1] = p1[1];
  P.W[2] = p2[0]; P.V[2] = p2[1]; P.W[3] = p3[0]; P.V[3] = p3[1];
  P.W[4] = p4[0]; P.V[4] = p4[1]; P.W[5] = p5[0]; P.V[5] = p5[1];
  P.W[6] = p6[0]; P.V[6] = p6[1]; P.W[7] = p7[0]; P.V[7] = p7[1];
  P.W[8] = p8[0]; P.V[8] = p8[1];
  P.bv = __uint_as_float(bvu); P.Eb = (int)ebu; P.Ead = (int)eau;
}

// 16 DP steps. NO DS ops inside (bnd values captured to vb/cF registers).
// G = guarded (fill/drain) variant: c==0 seed + active-masking only.
template <bool G>
__device__ __forceinline__ void steps16(const Pref& P, int t0, int l, int tid,
                                        bool isL0, bool par, uint32_t shE,
                                        uint32_t shO, float rsc, float curv,
                                        f4& vb0, f4& vb1, f4& vb2, f4& vb3,
                                        float& cF, float& x1, float& x2,
                                        float& areg) {
  vb0[0] = cF;  // batch word 0 = col t0-64 (prev chunk's s=15 capture)
#pragma unroll
  for (int s = 0; s < 16; ++s) {
    uint32_t wd, vd;
    if ((s & 1) == 0) { wd = P.W[s >> 1]; vd = P.V[s >> 1]; }
    else {
      wd = par ? P.W[(s + 1) >> 1] : P.W[s >> 1];
      vd = par ? P.V[(s + 1) >> 1] : P.V[s >> 1];
    }
    const uint32_t sh = (s & 1) ? shO : shE;
    const float d1 = __uint_as_float((wd << sh) & 0xffff0000u);
    const float d2 = __uint_as_float((vd << sh) & 0xffff0000u);
    const float k1 = __builtin_amdgcn_exp2f(d1 * -L2E);  // off-chain
    const float k2 = __builtin_amdgcn_exp2f(d2 * -L2E);
    float aa = areg;
    int c = 0;
    if (G) {
      c = t0 + s - l;
      aa = (tid == 0 && c == 0) ? 1.0f : aa;  // P(R[0][0]=0)=1 seed
    }
    const float k1s1 = k1 * (aa + x1);  // off-chain
    const float k2s2 = k2 * (x1 + x2);  // off-chain
    // chain: dpp -> mul -> cndmask -> fma -> fma
    const float bsh = dpp_shr1(x2) * rsc;
    const float bb = isL0 ? rdlane(curv, s) : bsh;
    const float x1n = fmaf(k1, bb, k1s1);
    const float x2n = fmaf(k2, x1n, k2s2);
    // capture for lane-63 batched bnd write (m = s+1; s=15 -> carry)
    if (s < 3)       vb0[s + 1] = x2n;
    else if (s < 7)  vb1[s - 3] = x2n;
    else if (s < 11) vb2[s - 7] = x2n;
    else if (s < 15) vb3[s - 11] = x2n;
    else             cF = x2n;  // pre-renorm: scale = this chunk's E
    if (G) {
      const bool act = (unsigned)c < 512u;
      x1 = act ? x1n : x1;
      x2 = act ? x2n : x2;
    } else {
      x1 = x1n;
      x2 = x2n;
    }
    areg = bb;
  }
}

// Coalesced stage of col-block [CS, CS+16): instr i, lane j: row 16i+(j>>2),
// 16B at col CS+(j&3)*4 -> 16 lines/instr.
#define STAGE_ISSUE(CS) do {                                                        \
    const int v0_ = voBase + ((CS) << 2);                                           \
    asm volatile("buffer_load_dwordx4 %0, %1, %2, 0 offen" : "=v"(g0) : "v"(v0_), "s"(srd));             \
    asm volatile("buffer_load_dwordx4 %0, %1, %2, 0 offen" : "=v"(g1) : "v"(v0_ + 1*32768), "s"(srd));   \
    asm volatile("buffer_load_dwordx4 %0, %1, %2, 0 offen" : "=v"(g2) : "v"(v0_ + 2*32768), "s"(srd));   \
    asm volatile("buffer_load_dwordx4 %0, %1, %2, 0 offen" : "=v"(g3) : "v"(v0_ + 3*32768), "s"(srd));   \
    asm volatile("buffer_load_dwordx4 %0, %1, %2, 0 offen" : "=v"(g4) : "v"(v0_ + 4*32768), "s"(srd));   \
    asm volatile("buffer_load_dwordx4 %0, %1, %2, 0 offen" : "=v"(g5) : "v"(v0_ + 5*32768), "s"(srd));   \
    asm volatile("buffer_load_dwordx4 %0, %1, %2, 0 offen" : "=v"(g6) : "v"(v0_ + 6*32768), "s"(srd));   \
    asm volatile("buffer_load_dwordx4 %0, %1, %2, 0 offen" : "=v"(g7) : "v"(v0_ + 7*32768), "s"(srd));   \
} while (0)

// vmcnt(0) safe: the 8 stage loads are the only in-flight VMEM.
// b64 stores: banks = uniform 4 dwords/bank (conflict-free at RW=66).
#define STAGE_WRITE(CS) do {                                                        \
    asm volatile("s_waitcnt vmcnt(0)"                                               \
        : "+v"(g0), "+v"(g1), "+v"(g2), "+v"(g3),                                   \
          "+v"(g4), "+v"(g5), "+v"(g6), "+v"(g7)::);                                \
    const int ew_ = (((CS) & 127) >> 1) + ((l & 3) << 1);                           \
    const int r_ = l >> 2;                                                          \
    *(uint2*)&dring[w][r_][ew_]       = packw2(g0);                                 \
    *(uint2*)&dring[w][r_ + 16][ew_]  = packw2(g1);                                 \
    *(uint2*)&dring[w][r_ + 32][ew_]  = packw2(g2);                                 \
    *(uint2*)&dring[w][r_ + 48][ew_]  = packw2(g3);                                 \
    *(uint2*)&dring[w][r_ + 64][ew_]  = packw2(g4);                                 \
    *(uint2*)&dring[w][r_ + 80][ew_]  = packw2(g5);                                 \
    *(uint2*)&dring[w][r_ + 96][ew_]  = packw2(g6);                                 \
    *(uint2*)&dring[w][r_ + 112][ew_] = packw2(g7);                                 \
} while (0)

#define BODY(PC, PN, MC) do {                                                       \
    const int t0_ = 16 * (MC) - ow;                                                 \
    /* consume fence for PC's prefetched reads (rule #18: sched_barrier) */         \
    asm volatile("s_waitcnt lgkmcnt(0)" ::: "memory");                              \
    __builtin_amdgcn_sched_barrier(0);                                              \
    const bool doStage_ = (t0_ >= 0) && (t0_ <= 480);                               \
    if (doStage_) STAGE_ISSUE(t0_ + 16);                                            \
    if (t0_ >= 0 && t0_ < LOCAL) {                                                  \
      const int ENpre_ = dpp_shr1_i(E);                                             \
      const bool inact_ = (x1 == 0.0f) && (x2 == 0.0f);                             \
      if (w > 0 && t0_ == 0) E = PC.Ead;         /* whole-wave scale adoption */    \
      else if (inact_ && !isL0) E = ENpre_;      /* track left neighbor */          \
      float curv_ = 0.0f;                                                           \
      if (w > 0 && t0_ < 512) {                                                     \
        const int E0_ = __builtin_amdgcn_readfirstlane(E);                          \
        curv_ = ldexpf(PC.bv, PC.Eb - E0_);      /* exact scale reconcile */        \
      }                                                                             \
      if (l == 63) bwrE[t0_ >> 4] = E;                                              \
      const int EN2_ = dpp_shr1_i(E);                                               \
      int dE_ = EN2_ - E;                                                           \
      dE_ = dE_ < -126 ? -126 : (dE_ > 126 ? 126 : dE_);                            \
      const float rsc_ = __int_as_float((127 + dE_) << 23);                         \
      if (t0_ >= 64 && t0_ <= 496)                                                  \
        steps16<false>(PC, t0_, l, tid, isL0, par, shE, shO, rsc_, curv_,           \
                       vb0, vb1, vb2, vb3, cF, x1, x2, areg);                       \
      else                                                                          \
        steps16<true>(PC, t0_, l, tid, isL0, par, shE, shO, rsc_, curv_,            \
                      vb0, vb1, vb2, vb3, cF, x1, x2, areg);                        \
      /* per-lane renorm: recenter max(x1,x2) exponent to 2^-10 */                  \
      const int bx_ = (__float_as_int(x1) >> 23) & 255;                             \
      const int by_ = (__float_as_int(x2) >> 23) & 255;                             \
      int exm_ = bx_ > by_ ? bx_ : by_;                                             \
      int sh_ = (exm_ > 0) ? (117 - exm_) : 0;                                      \
      sh_ = sh_ < -110 ? -110 : sh_;                                                \
      const float sc_ = __int_as_float((127 + sh_) << 23);                          \
      x1 *= sc_; x2 *= sc_; areg *= sc_; E -= sh_;                                  \
      /* lane-63 batched bnd write: cols [t0-64, t0-49], 4x ds_write_b128 */        \
      if (t0_ >= 64 && t0_ <= 560 && l == 63) {                                     \
        f4* bp_ = (f4*)&bwr[t0_ - 64];                                              \
        bp_[0] = vb0; bp_[1] = vb1; bp_[2] = vb2; bp_[3] = vb3;                     \
      }                                                                             \
    }                                                                               \
    if (doStage_) STAGE_WRITE(t0_ + 16);                                            \
    prefetch_asm(PN, 16 * ((MC) + 1) - ow, w, l, ringB, brdB, brdEB);               \
    /* counted wait: 12 prefetch reads stay outstanding; all earlier DS     */      \
    /* (bnd/stage/bndE writes) are complete by FIFO order -> barrier-safe.  */      \
    asm volatile("s_waitcnt lgkmcnt(12)" ::: "memory");                             \
    __builtin_amdgcn_s_barrier();                                                   \
} while (0)

__global__ __launch_bounds__(256, 1) void sdtw_kernel(const float* __restrict__ D,
                                                      float* __restrict__ out) {
  static_assert(NCHUNK % 2 == 0, "loop is 2x unrolled");
  __shared__ uint32_t dring[NWAVE][128][RW];      // per-wave PRIVATE bf16 ring
  __shared__ alignas(16) float bnd[NWAVE + 1][BROW];  // [4] = dump row
  __shared__ int bndE[NWAVE][36];                 // per-chunk lane-63 scale E
  const int tid = threadIdx.x;
  const int w = tid >> 6, l = tid & 63, b = blockIdx.x;

  u32x4 srd;  // raw buffer descriptor over D
  const uint64_t base = (uint64_t)(const void*)D;
  srd[0] = (unsigned)base;
  srd[1] = (unsigned)(base >> 32) & 0xffffu;  // stride=0
  srd[2] = 64u * 512u * 512u * 4u;            // num_records (bytes)
  srd[3] = 0x00020000u;

  const int ow = w * DELTA;
  const bool isL0 = (l == 0);
  const bool par = (l & 1) != 0;
  const uint32_t shE = par ? 0u : 16u;
  const uint32_t shO = par ? 16u : 0u;
  const int voBase = (((b << 9) + (w << 7) + (l >> 2)) << 11) + ((l & 3) << 4);

  float* __restrict__ bwr = &bnd[(w == NWAVE - 1) ? NWAVE : w][0];
  int* __restrict__ bwrE = &bndE[w][0];
  const uint32_t ringB = (uint32_t)(uintptr_t)&dring[w][2 * l][0];
  const uint32_t brdB = (uint32_t)(uintptr_t)&bnd[(w == 0) ? 0 : (w - 1)][0];
  const uint32_t brdEB = (uint32_t)(uintptr_t)&bndE[(w == 0) ? 0 : (w - 1)][0];

  float x1 = 0.0f, x2 = 0.0f, areg = 0.0f;  // P(INF) = 0
  int E = 0;                                // per-lane scale exponent

  f4 g0, g1, g2, g3, g4, g5, g6, g7;        // staged f32 col-block
  f4 vb0{}, vb1{}, vb2{}, vb3{};            // lane-63 bnd batch
  float cF = 0.0f;                          // s=15 carry (col t0-64)
  Pref PA{}, PB{};

  // prologue: stage cols [0,16) (wave-private), prefetch for chunk 0
  STAGE_ISSUE(0);
  STAGE_WRITE(0);
  prefetch_asm(PA, -ow, w, l, ringB, brdB, brdEB);

  for (int mc = 0; mc < NCHUNK; mc += 2) {
    BODY(PA, PB, mc);
    BODY(PB, PA, mc + 1);
  }

  if (tid == NWAVE * 64 - 1) {
    // x2 * 2^E = exp(-R[512][512]);  v_log_f32 is log2
    const float Rv = -(__builtin_amdgcn_logf(x2) + (float)E);
    out[b] = Rv * LN2;
  }
}

extern "C" void kernel_launch(void* const* d_in, const int* in_sizes, int n_in,
                              void* d_out, int out_size, void* d_ws, size_t ws_size,
                              hipStream_t stream) {
  const float* D = (const float*)d_in[0];
  float* out = (float*)d_out;
  hipLaunchKernelGGL(sdtw_kernel, dim3(64), dim3(NWAVE * 64), 0, stream, D, out);
}